// Round 1
// baseline (181.467 us; speedup 1.0000x reference)
//
#include <hip/hip_runtime.h>
#include <cstdint>

// Problem constants
#define B_   64
#define CI_  384
#define CO_  384
#define HW_  784
#define E_   8

typedef unsigned short ushort_t;
typedef unsigned int   uint_t;

typedef __attribute__((ext_vector_type(8))) short bf16x8;   // 8 bf16 (4 VGPRs)
typedef __attribute__((ext_vector_type(4))) float f32x4;    // MFMA accumulator

__device__ __forceinline__ ushort_t f2bf_rne(float f) {
  uint_t u = __builtin_bit_cast(uint_t, f);
  u += 0x7fffu + ((u >> 16) & 1u);
  return (ushort_t)(u >> 16);
}

// Pack truncated-bf16 of (f0 -> low ushort, f1 -> high ushort) in one v_perm_b32.
__device__ __forceinline__ uint_t pack_bf16_trunc(float f0, float f1) {
  return __builtin_amdgcn_perm(__builtin_bit_cast(uint_t, f1),   // S0 -> bytes 4..7
                               __builtin_bit_cast(uint_t, f0),   // S1 -> bytes 0..3
                               0x07060302u);                     // {f1.b3,f1.b2,f0.b3,f0.b2}
}

// ---------------------------------------------------------------------------
// Kernel 1: agg[b,o,i] = sum_e r[b,e] * w[e,o,i], stored bf16 into workspace.
// (unchanged from previous round -- not the bottleneck)
// ---------------------------------------------------------------------------
__global__ __launch_bounds__(256) void agg_kernel(const float* __restrict__ rw,
                                                  const float* __restrict__ w,
                                                  ushort_t* __restrict__ agg) {
  __shared__ float r[B_ * E_];  // 512 routing weights
  const int tid = threadIdx.x;
  r[tid]       = rw[tid];
  r[tid + 256] = rw[tid + 256];
  const int base = blockIdx.x * 512 + tid * 2;  // flat (o,i) pair index
  float2 wv[E_];
#pragma unroll
  for (int e = 0; e < E_; ++e)
    wv[e] = *(const float2*)&w[e * (CO_ * CI_) + base];
  __syncthreads();
  const int b0 = blockIdx.y * 16;
#pragma unroll 4
  for (int bi = 0; bi < 16; ++bi) {
    const int b = b0 + bi;
    float ax = 0.f, ay = 0.f;
#pragma unroll
    for (int e = 0; e < E_; ++e) {
      const float rv = r[b * E_ + e];
      ax += rv * wv[e].x;
      ay += rv * wv[e].y;
    }
    const uint_t v = (uint_t)f2bf_rne(ax) | ((uint_t)f2bf_rne(ay) << 16);
    *(uint_t*)&agg[(size_t)b * (CO_ * CI_) + base] = v;
  }
}

// ---------------------------------------------------------------------------
// Kernel 2: per-sample GEMM  out[b] = agg[b](384x384, bf16) @ x[b](384x784, f32)
// BM=BN=128, BK=32, 256 thr = 4 waves 2x2, wave tile 64x64 (4x4 16x16 frags).
//
// NEW: double-buffered 2-phase software pipeline (guide T3-minimum + T14):
//   per K-step: issue A global_load_lds + 8x global_load_dwordx2 (B) for tile
//   t+1 -> sched_barrier -> ds_read+MFMA tile t -> sched_barrier -> vmcnt-wait
//   lands in the pack+ds_write_b128 of tile t+1 -> single barrier.
//   HBM latency is covered by the MFMA cluster instead of serialized.
//
// B staging: thread owns col pair n0=2*(tid&63), k rows kh..kh+7 (kh=8*wave).
//   8x float2 loads (coalesced 512B/wave/instr), pack to bf16, two
//   ds_write_b128 per thread. 16B slot-spread swizzle +(((n>>3)&1)<<3) ushorts
//   inside the 80B row makes both write and read conflict-free per 8-lane grp.
// ---------------------------------------------------------------------------
#define BM 128
#define BN 128
#define BK 32
#define KIT (CI_ / BK)     // 12
#define BS_STRIDE 40       // ushorts per Bs row = 80 B (4 data slots + 1 pad slot)

__global__ __launch_bounds__(256) void moe_gemm(const float* __restrict__ X,
                                                const ushort_t* __restrict__ Agg,
                                                float* __restrict__ Out) {
  __shared__ __align__(16) ushort_t As[2][BM * BK];         // 2 x 8 KB
  __shared__ __align__(16) ushort_t Bs[2][BN * BS_STRIDE];  // 2 x 10 KB

  const int tid  = threadIdx.x;
  const int lane = tid & 63;
  const int wave = tid >> 6;
  const int wm = wave & 1, wn = wave >> 1;

  // XCD-aware decomposition: b = (y/21)*8 + x; rem = y%21; mt = rem/7; nt = rem%7
  const int bx = blockIdx.x;           // 0..7  == XCD id (linear%8 round-robin)
  const int by = blockIdx.y;           // 0..167
  const int bg  = by / 21;
  const int rem = by - bg * 21;
  const int mt  = rem / 7;
  const int nt  = rem - mt * 7;
  const int b   = bg * 8 + bx;

  const ushort_t* Ab = Agg + (size_t)b * CO_ * CI_ + mt * BM * CI_;
  const float*    Xb = X   + (size_t)b * CI_ * HW_;

  // ---- B-staging coords: col pair n0, n0+1; k rows kh..kh+7 ----
  const int nh  = tid & 63;
  const int n0  = nh * 2;
  const int kh  = (tid >> 6) * 8;            // 0,8,16,24 per wave
  const int gn0 = nt * BN + n0;
  const int gnc = gn0 > (HW_ - 2) ? (HW_ - 2) : gn0;  // clamp (pair stays in-bounds)
  const float* Xcol = Xb + (size_t)kh * HW_ + gnc;

  // B LDS write indices (ushort units) with 16B slot-spread swizzle
  const int bwr0 = n0 * BS_STRIDE + kh + (((n0 >> 3) & 1) << 3);
  const int bwr1 = (n0 + 1) * BS_STRIDE + kh + ((((n0 + 1) >> 3) & 1) << 3);

  const int l15 = lane & 15;
  const int lq  = lane >> 4;
  const int xqA = lq ^ ((l15 >> 1) & 3);     // swizzled q for A-frag reads
  // Fragment read bases (ushort units); +mf*512 / +nf*640 per fragment step.
  const int arow = ((wm * 64 + l15) * 4 + xqA) * 8;
  const int brow = (wn * 64 + l15) * BS_STRIDE + lq * 8 + (((l15 >> 3) & 1) << 3);

  // A-staging source (m,q): slot s holds (m=s>>2, q=(s&3)^((s>>3)&3))
  const int sm0 = tid >> 2,           sq0 = (tid & 3) ^ ((tid >> 3) & 3);
  const int sm1 = (tid + 256) >> 2,   sq1 = (tid & 3) ^ (((tid + 256) >> 3) & 3);

  f32x4 acc[4][4];
#pragma unroll
  for (int i = 0; i < 4; ++i)
#pragma unroll
    for (int j = 0; j < 4; ++j)
      acc[i][j] = (f32x4)0.f;

  float2 vr[8];   // in-flight B tile (registers, statically indexed)

#define STAGE_A(PB, K0)                                                        \
  {                                                                            \
    const ushort_t* s0_ = Ab + sm0 * CI_ + (K0) + sq0 * 8;                     \
    __builtin_amdgcn_global_load_lds(                                          \
        (const __attribute__((address_space(1))) uint_t*)s0_,                  \
        (__attribute__((address_space(3))) uint_t*)&As[PB][tid * 8], 16, 0, 0);\
    const ushort_t* s1_ = Ab + sm1 * CI_ + (K0) + sq1 * 8;                     \
    __builtin_amdgcn_global_load_lds(                                          \
        (const __attribute__((address_space(1))) uint_t*)s1_,                  \
        (__attribute__((address_space(3))) uint_t*)&As[PB][(tid + 256) * 8],   \
        16, 0, 0);                                                             \
  }

#define LOADB(K0)                                                              \
  {                                                                            \
    const float* p_ = Xcol + (size_t)(K0) * HW_;                               \
    _Pragma("unroll") for (int k_ = 0; k_ < 8; ++k_)                           \
        vr[k_] = *(const float2*)(p_ + (size_t)k_ * HW_);                      \
  }

#define PACKB(PB)                                                              \
  {                                                                            \
    const uint_t e0_ = pack_bf16_trunc(vr[0].x, vr[1].x);                      \
    const uint_t e1_ = pack_bf16_trunc(vr[2].x, vr[3].x);                      \
    const uint_t e2_ = pack_bf16_trunc(vr[4].x, vr[5].x);                      \
    const uint_t e3_ = pack_bf16_trunc(vr[6].x, vr[7].x);                      \
    *(uint4*)&Bs[PB][bwr0] = make_uint4(e0_, e1_, e2_, e3_);                   \
    const uint_t o0_ = pack_bf16_trunc(vr[0].y, vr[1].y);                      \
    const uint_t o1_ = pack_bf16_trunc(vr[2].y, vr[3].y);                      \
    const uint_t o2_ = pack_bf16_trunc(vr[4].y, vr[5].y);                      \
    const uint_t o3_ = pack_bf16_trunc(vr[6].y, vr[7].y);                      \
    *(uint4*)&Bs[PB][bwr1] = make_uint4(o0_, o1_, o2_, o3_);                   \
  }

#define COMPUTE(CB)                                                            \
  {                                                                            \
    bf16x8 a_[4], b_[4];                                                       \
    _Pragma("unroll") for (int mf_ = 0; mf_ < 4; ++mf_)                        \
        a_[mf_] = *(const bf16x8*)&As[CB][arow + mf_ * (16 * BK)];             \
    _Pragma("unroll") for (int nf_ = 0; nf_ < 4; ++nf_)                        \
        b_[nf_] = *(const bf16x8*)&Bs[CB][brow + nf_ * (16 * BS_STRIDE)];      \
    __builtin_amdgcn_s_setprio(1);                                             \
    _Pragma("unroll") for (int mf_ = 0; mf_ < 4; ++mf_)                        \
        _Pragma("unroll") for (int nf_ = 0; nf_ < 4; ++nf_)                    \
            acc[mf_][nf_] = __builtin_amdgcn_mfma_f32_16x16x32_bf16(           \
                a_[mf_], b_[nf_], acc[mf_][nf_], 0, 0, 0);                     \
    __builtin_amdgcn_s_setprio(0);                                             \
  }

// One pipelined K-step: prefetch tile NT into PB while computing CB.
// sched_barrier(0) fences keep hipcc from hoisting the pack (and its vmcnt
// wait) above the MFMA cluster -- that overlap IS the optimization.
#define BODY(CB, PB, NT)                                                       \
  {                                                                            \
    STAGE_A(PB, (NT) * BK);                                                    \
    LOADB((NT) * BK);                                                          \
    __builtin_amdgcn_sched_barrier(0);                                         \
    COMPUTE(CB);                                                               \
    __builtin_amdgcn_sched_barrier(0);                                         \
    PACKB(PB);                                                                 \
    __syncthreads();                                                           \
  }

  // ---- Prologue: stage tile 0 into buffer 0 ----
  STAGE_A(0, 0);
  LOADB(0);
  PACKB(0);
  __syncthreads();

  // ---- Main pipeline: 12 tiles, compute t while tile t+1 is in flight ----
#pragma unroll 1
  for (int t = 0; t < 10; t += 2) {
    BODY(0, 1, t + 1);
    BODY(1, 0, t + 2);
  }
  BODY(0, 1, 11);
  COMPUTE(1);   // tile 11, no prefetch

  // ---- Epilogue: C/D layout col=lane&15, row=(lane>>4)*4+reg ----
  float* Ob = Out + (size_t)b * CO_ * HW_;
#pragma unroll
  for (int mf = 0; mf < 4; ++mf) {
#pragma unroll
    for (int nf = 0; nf < 4; ++nf) {
      const int n = nt * BN + wn * 64 + nf * 16 + l15;
      if (n < HW_) {
        const int mbase = mt * BM + wm * 64 + mf * 16 + lq * 4;
#pragma unroll
        for (int r = 0; r < 4; ++r)
          Ob[(size_t)(mbase + r) * HW_ + n] = acc[mf][nf][r];
      }
    }
  }
}

// ---------------------------------------------------------------------------
extern "C" void kernel_launch(void* const* d_in, const int* in_sizes, int n_in,
                              void* d_out, int out_size, void* d_ws, size_t ws_size,
                              hipStream_t stream) {
  const float* x  = (const float*)d_in[0];  // [64,384,28,28] f32
  const float* rw = (const float*)d_in[1];  // [64,8] f32
  const float* w  = (const float*)d_in[2];  // [8,384,384] f32
  float* out = (float*)d_out;               // [64,384,28,28] f32
  ushort_t* agg = (ushort_t*)d_ws;          // [64,384,384] bf16 = 18.9 MB scratch

  agg_kernel<<<dim3((CO_ * CI_) / 512, 4), 256, 0, stream>>>(rw, w, agg);
  moe_gemm<<<dim3(8, 168), 256, 0, stream>>>(x, agg, out);
}

// Round 2
// 178.160 us; speedup vs baseline: 1.0186x; 1.0186x over previous
//
#include <hip/hip_runtime.h>
#include <cstdint>

// Problem constants
#define B_   64
#define CI_  384
#define CO_  384
#define HW_  784
#define E_   8
#define G_   (CI_ / 8)   // 48 ci-octets

typedef unsigned short ushort_t;
typedef unsigned int   uint_t;

typedef __attribute__((ext_vector_type(8))) short bf16x8;   // 8 bf16 (4 VGPRs)
typedef __attribute__((ext_vector_type(4))) float f32x4;    // MFMA accumulator

__device__ __forceinline__ ushort_t f2bf_rne(float f) {
  uint_t u = __builtin_bit_cast(uint_t, f);
  u += 0x7fffu + ((u >> 16) & 1u);
  return (ushort_t)(u >> 16);
}

// Pack truncated-bf16 of (f0 -> low ushort, f1 -> high ushort) in one v_perm_b32.
__device__ __forceinline__ uint_t pack_bf16_trunc(float f0, float f1) {
  return __builtin_amdgcn_perm(__builtin_bit_cast(uint_t, f1),   // S0 -> bytes 4..7
                               __builtin_bit_cast(uint_t, f0),   // S1 -> bytes 0..3
                               0x07060302u);                     // {f1.b3,f1.b2,f0.b3,f0.b2}
}

// ---------------------------------------------------------------------------
// Kernel 1 (fused prep):
//  blocks [0, 1152):   agg[b,o,i] = sum_e r[b,e]*w[e,o,i] -> bf16 (unchanged math)
//  blocks [1152, 4224): xq[b][g][hw][j] = bf16(x[b][g*8+j][hw])  (ci-octet
//                       interleave so GEMM B-frags are 16B-contiguous per lane).
//  Both paths are BW-bound; fusing them in one dispatch overlaps them.
// ---------------------------------------------------------------------------
#define AGG_BLOCKS 1152              // (CO_*CI_/512) * 4
#define XQ_BLOCKS  (G_ * B_)         // 3072

__global__ __launch_bounds__(256) void prep(const float* __restrict__ rw,
                                            const float* __restrict__ w,
                                            const float* __restrict__ x,
                                            ushort_t* __restrict__ agg,
                                            ushort_t* __restrict__ xq) {
  __shared__ float r[B_ * E_];  // used by agg path only
  const int blk = blockIdx.x;
  const int tid = threadIdx.x;

  if (blk < AGG_BLOCKS) {
    // ---- agg path (identical math to the verified agg_kernel) ----
    r[tid]       = rw[tid];
    r[tid + 256] = rw[tid + 256];
    const int bxa = blk % 288;
    const int bya = blk / 288;
    const int base = bxa * 512 + tid * 2;  // flat (o,i) pair index
    float2 wv[E_];
#pragma unroll
    for (int e = 0; e < E_; ++e)
      wv[e] = *(const float2*)&w[e * (CO_ * CI_) + base];
    __syncthreads();
    const int b0 = bya * 16;
#pragma unroll 4
    for (int bi = 0; bi < 16; ++bi) {
      const int b = b0 + bi;
      float ax = 0.f, ay = 0.f;
#pragma unroll
      for (int e = 0; e < E_; ++e) {
        const float rv = r[b * E_ + e];
        ax += rv * wv[e].x;
        ay += rv * wv[e].y;
      }
      const uint_t v = (uint_t)f2bf_rne(ax) | ((uint_t)f2bf_rne(ay) << 16);
      *(uint_t*)&agg[(size_t)b * (CO_ * CI_) + base] = v;
    }
  } else {
    // ---- xq path: 8-row interleave + f32->bf16 (truncation, as before) ----
    const int idx = blk - AGG_BLOCKS;
    const int g = idx % G_;
    const int b = idx / G_;
    const float* xp = x + ((size_t)b * CI_ + g * 8) * HW_;
    ushort_t* op = xq + (((size_t)b * G_ + g) * HW_) * 8;
#pragma unroll
    for (int c = 0; c < 4; ++c) {
      const int hw = c * 256 + tid;
      if (hw < HW_) {
        float v[8];
#pragma unroll
        for (int j = 0; j < 8; ++j) v[j] = xp[(size_t)j * HW_ + hw];
        uint4 u;
        u.x = pack_bf16_trunc(v[0], v[1]);
        u.y = pack_bf16_trunc(v[2], v[3]);
        u.z = pack_bf16_trunc(v[4], v[5]);
        u.w = pack_bf16_trunc(v[6], v[7]);
        *(uint4*)&op[hw * 8] = u;   // 16B chunk = one B-frag lane slice
      }
    }
  }
}

// ---------------------------------------------------------------------------
// Kernel 2: LDS-free, barrier-free per-sample GEMM.
//   out[b](384x784) = agg[b](384x384 bf16) @ x[b](384x784, as xq bf16)
// 1 wave per block, tile 48(co) x 112(hw), BK=32 -> 12 K-steps, zero tails
// (384=8*48, 784=7*112, 384=12*32). Per K-step: 3 A-frag + 7 B-frag dwordx4
// loads (both fragment-contiguous thanks to layouts) + 21 MFMA. Register
// double-buffer across K-steps; latency hidden by TLP (2 waves/SIMD, 14
// blocks/CU queued) with compiler-counted vmcnt -- no __syncthreads at all.
// Grid (8, 448): x == XCD (linear%8); y packs (bg, mt, nt) so all 56 tiles of
// one b share an XCD (agg_b 288KB + xq_b 602KB stay L2-hot).
// ---------------------------------------------------------------------------
#define TM 48              // rows per block (3 m-frags)
#define TN 112             // cols per block (7 n-frags)
#define KIT 12             // 384 / 32

__global__ __launch_bounds__(64, 2) void moe_gemm2(const ushort_t* __restrict__ Agg,
                                                   const ushort_t* __restrict__ Xq,
                                                   float* __restrict__ Out) {
  const int lane = threadIdx.x;
  const int l15 = lane & 15;
  const int lq  = lane >> 4;

  const int bx = blockIdx.x;          // 0..7  == XCD id
  const int by = blockIdx.y;          // 0..447
  const int bg  = by / 56;
  const int rem = by - bg * 56;
  const int mt  = rem / 7;
  const int nt  = rem - mt * 7;
  const int b   = bg * 8 + bx;

  // A-frag lane base: row m = mt*48 + mf*16 + l15, k = kk*32 + lq*8 (contiguous 16B)
  const ushort_t* Abase = Agg + (size_t)b * CO_ * CI_ + (size_t)(mt * TM + l15) * CI_ + lq * 8;
  // B-frag lane base: chunk (b, g=kk*4+lq, n=nt*112 + nf*16 + l15), 16B each
  const ushort_t* Bbase = Xq + (((size_t)b * G_ + lq) * HW_ + (nt * TN + l15)) * 8;

  f32x4 acc[3][7];
#pragma unroll
  for (int i = 0; i < 3; ++i)
#pragma unroll
    for (int j = 0; j < 7; ++j)
      acc[i][j] = (f32x4)0.f;

  bf16x8 a0[3], a1[3], b0v[7], b1v[7];

#define LA(dst, KK)                                                            \
  {                                                                            \
    _Pragma("unroll") for (int mf_ = 0; mf_ < 3; ++mf_)                        \
        dst[mf_] = *(const bf16x8*)(Abase + (KK) * 32 + mf_ * (16 * CI_));     \
  }
#define LB(dst, KK)                                                            \
  {                                                                            \
    _Pragma("unroll") for (int nf_ = 0; nf_ < 7; ++nf_)                        \
        dst[nf_] = *(const bf16x8*)(Bbase + (KK) * (4 * HW_ * 8) + nf_ * 128); \
  }
#define MM(A_, B_)                                                             \
  {                                                                            \
    _Pragma("unroll") for (int mf_ = 0; mf_ < 3; ++mf_)                        \
        _Pragma("unroll") for (int nf_ = 0; nf_ < 7; ++nf_)                    \
            acc[mf_][nf_] = __builtin_amdgcn_mfma_f32_16x16x32_bf16(           \
                A_[mf_], B_[nf_], acc[mf_][nf_], 0, 0, 0);                     \
  }

  LA(a0, 0); LB(b0v, 0);
#pragma unroll 1
  for (int t = 0; t < 5; ++t) {
    const int k1 = 2 * t + 1, k2 = 2 * t + 2;
    LA(a1, k1); LB(b1v, k1);
    MM(a0, b0v);               // covers latency of (a1,b1) loads
    LA(a0, k2); LB(b0v, k2);
    MM(a1, b1v);               // covers latency of (a0,b0) loads
  }
  LA(a1, 11); LB(b1v, 11);
  MM(a0, b0v);
  MM(a1, b1v);

  // ---- Epilogue: C/D layout col=lane&15 (n), row=(lane>>4)*4+reg (m) ----
  // No bounds checks: 784 = 7*112 and 384 = 8*48 exactly.
  float* Ob = Out + (size_t)b * CO_ * HW_;
#pragma unroll
  for (int mf = 0; mf < 3; ++mf) {
#pragma unroll
    for (int nf = 0; nf < 7; ++nf) {
      const int n = nt * TN + nf * 16 + l15;
      const int mbase = mt * TM + mf * 16 + lq * 4;
#pragma unroll
      for (int r = 0; r < 4; ++r)
        Ob[(size_t)(mbase + r) * HW_ + n] = acc[mf][nf][r];
    }
  }
}

// ---------------------------------------------------------------------------
// Workspace layout: agg bf16 [64][384][384] = 18.9 MB at offset 0,
//                   xq  bf16 [64][48][784][8] = 38.5 MB after it. (57.4 MB total)
// ---------------------------------------------------------------------------
extern "C" void kernel_launch(void* const* d_in, const int* in_sizes, int n_in,
                              void* d_out, int out_size, void* d_ws, size_t ws_size,
                              hipStream_t stream) {
  const float* x  = (const float*)d_in[0];  // [64,384,28,28] f32
  const float* rw = (const float*)d_in[1];  // [64,8] f32
  const float* w  = (const float*)d_in[2];  // [8,384,384] f32
  float* out = (float*)d_out;               // [64,384,28,28] f32

  ushort_t* agg = (ushort_t*)d_ws;
  ushort_t* xq  = agg + (size_t)B_ * CO_ * CI_;   // + 18.9 MB

  prep<<<AGG_BLOCKS + XQ_BLOCKS, 256, 0, stream>>>(rw, w, x, agg, xq);
  moe_gemm2<<<dim3(8, 448), 64, 0, stream>>>(agg, xq, out);
}

// Round 3
// 176.207 us; speedup vs baseline: 1.0299x; 1.0111x over previous
//
#include <hip/hip_runtime.h>
#include <cstdint>

// Problem constants
#define B_   64
#define CI_  384
#define CO_  384
#define HW_  784
#define E_   8
#define G_   (CI_ / 8)   // 48 ci-octets

typedef unsigned short ushort_t;
typedef unsigned int   uint_t;

typedef __attribute__((ext_vector_type(8))) short bf16x8;   // 8 bf16 (4 VGPRs)
typedef __attribute__((ext_vector_type(4))) float f32x4;    // MFMA accumulator

__device__ __forceinline__ ushort_t f2bf_rne(float f) {
  uint_t u = __builtin_bit_cast(uint_t, f);
  u += 0x7fffu + ((u >> 16) & 1u);
  return (ushort_t)(u >> 16);
}

// Pack truncated-bf16 of (f0 -> low ushort, f1 -> high ushort) in one v_perm_b32.
__device__ __forceinline__ uint_t pack_bf16_trunc(float f0, float f1) {
  return __builtin_amdgcn_perm(__builtin_bit_cast(uint_t, f1),   // S0 -> bytes 4..7
                               __builtin_bit_cast(uint_t, f0),   // S1 -> bytes 0..3
                               0x07060302u);                     // {f1.b3,f1.b2,f0.b3,f0.b2}
}

// ---------------------------------------------------------------------------
// Kernel 1 (fused prep):
//  blocks [0, 288):    agg[b,o,i] = sum_e r[b,e]*w[e,o,i] -> bf16.
//                      ONE block per 512-elem (o,i)-range covering ALL 64 b
//                      -> w is read exactly once (was 4x = +57MB HBM).
//                      Placed first: heavier blocks start early, overlap xq.
//  blocks [288, 3360): xq[b][g][hw][j] = bf16(x[b][g*8+j][hw])  (ci-octet
//                      interleave so GEMM B-frags are 16B-contiguous per lane).
// ---------------------------------------------------------------------------
#define AGG_BLOCKS 288               // CO_*CI_/512
#define XQ_BLOCKS  (G_ * B_)         // 3072

__global__ __launch_bounds__(256) void prep(const float* __restrict__ rw,
                                            const float* __restrict__ w,
                                            const float* __restrict__ x,
                                            ushort_t* __restrict__ agg,
                                            ushort_t* __restrict__ xq) {
  __shared__ float r[B_ * E_];  // used by agg path only
  const int blk = blockIdx.x;
  const int tid = threadIdx.x;

  if (blk < AGG_BLOCKS) {
    // ---- agg path: 512 (o,i) elems x all 64 b ----
    r[tid]       = rw[tid];
    r[tid + 256] = rw[tid + 256];
    const int base = blk * 512 + tid * 2;  // flat (o,i) pair index
    float2 wv[E_];
#pragma unroll
    for (int e = 0; e < E_; ++e)
      wv[e] = *(const float2*)&w[e * (CO_ * CI_) + base];
    __syncthreads();
#pragma unroll 8
    for (int b = 0; b < B_; ++b) {
      float ax = 0.f, ay = 0.f;
#pragma unroll
      for (int e = 0; e < E_; ++e) {
        const float rv = r[b * E_ + e];
        ax += rv * wv[e].x;
        ay += rv * wv[e].y;
      }
      const uint_t v = (uint_t)f2bf_rne(ax) | ((uint_t)f2bf_rne(ay) << 16);
      *(uint_t*)&agg[(size_t)b * (CO_ * CI_) + base] = v;
    }
  } else {
    // ---- xq path: 8-row interleave + f32->bf16 (truncation, as before) ----
    const int idx = blk - AGG_BLOCKS;
    const int g = idx % G_;
    const int b = idx / G_;
    const float* xp = x + ((size_t)b * CI_ + g * 8) * HW_;
    ushort_t* op = xq + (((size_t)b * G_ + g) * HW_) * 8;
#pragma unroll
    for (int c = 0; c < 4; ++c) {
      const int hw = c * 256 + tid;
      if (hw < HW_) {
        float v[8];
#pragma unroll
        for (int j = 0; j < 8; ++j) v[j] = xp[(size_t)j * HW_ + hw];
        uint4 u;
        u.x = pack_bf16_trunc(v[0], v[1]);
        u.y = pack_bf16_trunc(v[2], v[3]);
        u.z = pack_bf16_trunc(v[4], v[5]);
        u.w = pack_bf16_trunc(v[6], v[7]);
        *(uint4*)&op[hw * 8] = u;   // 16B chunk = one B-frag lane slice
      }
    }
  }
}

// ---------------------------------------------------------------------------
// Kernel 2: LDS-free, barrier-free per-sample GEMM.
//   out[b](384x784) = agg[b](384x384 bf16) @ x[b](384x784, as xq bf16)
// 1 wave per block, tile 48(co) x 112(hw), BK=32 -> 12 K-steps, zero tails.
// NEW vs round 2: 3-deep register pipeline (loads issued 3 K-steps ahead,
// ~1600-2400 cyc latency cover vs ~800 at 2-deep -- the round-2 version was
// still vmcnt-stall-bound). ~220 VGPR, fits 2 waves/SIMD without spill.
// Grid (8, 448): x == XCD (linear%8); y packs (bg, mt, nt) so all 56 tiles of
// one b share an XCD (agg_b 288KB + xq_b 602KB stay L2/L3-hot).
// ---------------------------------------------------------------------------
#define TM 48              // rows per block (3 m-frags)
#define TN 112             // cols per block (7 n-frags)
#define KIT 12             // 384 / 32

__global__ __launch_bounds__(64, 2) void moe_gemm2(const ushort_t* __restrict__ Agg,
                                                   const ushort_t* __restrict__ Xq,
                                                   float* __restrict__ Out) {
  const int lane = threadIdx.x;
  const int l15 = lane & 15;
  const int lq  = lane >> 4;

  const int bx = blockIdx.x;          // 0..7  == XCD id
  const int by = blockIdx.y;          // 0..447
  const int bg  = by / 56;
  const int rem = by - bg * 56;
  const int mt  = rem / 7;
  const int nt  = rem - mt * 7;
  const int b   = bg * 8 + bx;

  // A-frag lane base: row m = mt*48 + mf*16 + l15, k = kk*32 + lq*8 (contiguous 16B)
  const ushort_t* Abase = Agg + (size_t)b * CO_ * CI_ + (size_t)(mt * TM + l15) * CI_ + lq * 8;
  // B-frag lane base: chunk (b, g=kk*4+lq, n=nt*112 + nf*16 + l15), 16B each
  const ushort_t* Bbase = Xq + (((size_t)b * G_ + lq) * HW_ + (nt * TN + l15)) * 8;

  f32x4 acc[3][7];
#pragma unroll
  for (int i = 0; i < 3; ++i)
#pragma unroll
    for (int j = 0; j < 7; ++j)
      acc[i][j] = (f32x4)0.f;

  bf16x8 A0[3], A1[3], A2[3], B0[7], B1[7], B2[7];

#define LA(dst, KK)                                                            \
  {                                                                            \
    _Pragma("unroll") for (int mf_ = 0; mf_ < 3; ++mf_)                        \
        dst[mf_] = *(const bf16x8*)(Abase + (KK) * 32 + mf_ * (16 * CI_));     \
  }
#define LB(dst, KK)                                                            \
  {                                                                            \
    _Pragma("unroll") for (int nf_ = 0; nf_ < 7; ++nf_)                        \
        dst[nf_] = *(const bf16x8*)(Bbase + (KK) * (4 * HW_ * 8) + nf_ * 128); \
  }
#define MM(A_, B_)                                                             \
  {                                                                            \
    _Pragma("unroll") for (int mf_ = 0; mf_ < 3; ++mf_)                        \
        _Pragma("unroll") for (int nf_ = 0; nf_ < 7; ++nf_)                    \
            acc[mf_][nf_] = __builtin_amdgcn_mfma_f32_16x16x32_bf16(           \
                A_[mf_], B_[nf_], acc[mf_][nf_], 0, 0, 0);                     \
  }

  // Prologue: 3 tiles in flight.
  LA(A0, 0); LB(B0, 0);
  LA(A1, 1); LB(B1, 1);
  LA(A2, 2); LB(B2, 2);

#pragma unroll 1
  for (int t = 0; t < 9; t += 3) {
    MM(A0, B0); LA(A0, t + 3); LB(B0, t + 3);
    MM(A1, B1); LA(A1, t + 4); LB(B1, t + 4);
    MM(A2, B2); LA(A2, t + 5); LB(B2, t + 5);
  }
  MM(A0, B0);   // k=9
  MM(A1, B1);   // k=10
  MM(A2, B2);   // k=11

  // ---- Epilogue: C/D layout col=lane&15 (n), row=(lane>>4)*4+reg (m) ----
  // No bounds checks: 784 = 7*112 and 384 = 8*48 exactly.
  float* Ob = Out + (size_t)b * CO_ * HW_;
#pragma unroll
  for (int mf = 0; mf < 3; ++mf) {
#pragma unroll
    for (int nf = 0; nf < 7; ++nf) {
      const int n = nt * TN + nf * 16 + l15;
      const int mbase = mt * TM + mf * 16 + lq * 4;
#pragma unroll
      for (int r = 0; r < 4; ++r)
        Ob[(size_t)(mbase + r) * HW_ + n] = acc[mf][nf][r];
    }
  }
}

// ---------------------------------------------------------------------------
// Workspace layout: agg bf16 [64][384][384] = 18.9 MB at offset 0,
//                   xq  bf16 [64][48][784][8] = 38.5 MB after it. (57.4 MB total)
// ---------------------------------------------------------------------------
extern "C" void kernel_launch(void* const* d_in, const int* in_sizes, int n_in,
                              void* d_out, int out_size, void* d_ws, size_t ws_size,
                              hipStream_t stream) {
  const float* x  = (const float*)d_in[0];  // [64,384,28,28] f32
  const float* rw = (const float*)d_in[1];  // [64,8] f32
  const float* w  = (const float*)d_in[2];  // [8,384,384] f32
  float* out = (float*)d_out;               // [64,384,28,28] f32

  ushort_t* agg = (ushort_t*)d_ws;
  ushort_t* xq  = agg + (size_t)B_ * CO_ * CI_;   // + 18.9 MB

  prep<<<AGG_BLOCKS + XQ_BLOCKS, 256, 0, stream>>>(rw, w, x, agg, xq);
  moe_gemm2<<<dim3(8, 448), 64, 0, stream>>>(agg, xq, out);
}

// Round 5
// 173.563 us; speedup vs baseline: 1.0455x; 1.0152x over previous
//
#include <hip/hip_runtime.h>
#include <cstdint>

// Problem constants
#define B_   64
#define CI_  384
#define CO_  384
#define HW_  784
#define E_   8
#define G_   (CI_ / 8)   // 48 ci-octets

typedef unsigned short ushort_t;
typedef unsigned int   uint_t;

typedef __attribute__((ext_vector_type(8))) short bf16x8;   // 8 bf16 (4 VGPRs)
typedef __attribute__((ext_vector_type(4))) float f32x4;    // MFMA accumulator

__device__ __forceinline__ ushort_t f2bf_rne(float f) {
  uint_t u = __builtin_bit_cast(uint_t, f);
  u += 0x7fffu + ((u >> 16) & 1u);
  return (ushort_t)(u >> 16);
}

// Pack truncated-bf16 of (f0 -> low ushort, f1 -> high ushort) in one v_perm_b32.
__device__ __forceinline__ uint_t pack_bf16_trunc(float f0, float f1) {
  return __builtin_amdgcn_perm(__builtin_bit_cast(uint_t, f1),   // S0 -> bytes 4..7
                               __builtin_bit_cast(uint_t, f0),   // S1 -> bytes 0..3
                               0x07060302u);                     // {f1.b3,f1.b2,f0.b3,f0.b2}
}

// ---------------------------------------------------------------------------
// Kernel 1 (fused prep):
//  blocks [0, 288):    agg[b,o,i] = sum_e r[b,e]*w[e,o,i] -> bf16 (w read once).
//  blocks [288, 3360): xq[b][g][hw][j] = bf16(x[b][g*8+j][hw])  (ci-octet
//                      interleave: 16B chunk (g,hw) == one GEMM B-frag slice).
// ---------------------------------------------------------------------------
#define AGG_BLOCKS 288               // CO_*CI_/512
#define XQ_BLOCKS  (G_ * B_)         // 3072

__global__ __launch_bounds__(256) void prep(const float* __restrict__ rw,
                                            const float* __restrict__ w,
                                            const float* __restrict__ x,
                                            ushort_t* __restrict__ agg,
                                            ushort_t* __restrict__ xq) {
  __shared__ float r[B_ * E_];  // used by agg path only
  const int blk = blockIdx.x;
  const int tid = threadIdx.x;

  if (blk < AGG_BLOCKS) {
    r[tid]       = rw[tid];
    r[tid + 256] = rw[tid + 256];
    const int base = blk * 512 + tid * 2;  // flat (o,i) pair index
    float2 wv[E_];
#pragma unroll
    for (int e = 0; e < E_; ++e)
      wv[e] = *(const float2*)&w[e * (CO_ * CI_) + base];
    __syncthreads();
#pragma unroll 8
    for (int b = 0; b < B_; ++b) {
      float ax = 0.f, ay = 0.f;
#pragma unroll
      for (int e = 0; e < E_; ++e) {
        const float rv = r[b * E_ + e];
        ax += rv * wv[e].x;
        ay += rv * wv[e].y;
      }
      const uint_t v = (uint_t)f2bf_rne(ax) | ((uint_t)f2bf_rne(ay) << 16);
      *(uint_t*)&agg[(size_t)b * (CO_ * CI_) + base] = v;
    }
  } else {
    const int idx = blk - AGG_BLOCKS;
    const int g = idx % G_;
    const int b = idx / G_;
    const float* xp = x + ((size_t)b * CI_ + g * 8) * HW_;
    ushort_t* op = xq + (((size_t)b * G_ + g) * HW_) * 8;
#pragma unroll
    for (int c = 0; c < 4; ++c) {
      const int hw = c * 256 + tid;
      if (hw < HW_) {
        float v[8];
#pragma unroll
        for (int j = 0; j < 8; ++j) v[j] = xp[(size_t)j * HW_ + hw];
        uint4 u;
        u.x = pack_bf16_trunc(v[0], v[1]);
        u.y = pack_bf16_trunc(v[2], v[3]);
        u.z = pack_bf16_trunc(v[4], v[5]);
        u.w = pack_bf16_trunc(v[6], v[7]);
        *(uint4*)&op[hw * 8] = u;   // 16B chunk = one B-frag lane slice
      }
    }
  }
}

// ---------------------------------------------------------------------------
// Kernel 2: m97-structure GEMM, both operands DMA-staged (zero VALU staging).
//   out[b](384x784) = agg[b](384x384 bf16) @ x[b] (as xq bf16)
// 256 thr = 4 waves (2x2), BM=BN=128 (N padded: 7 tiles, last 16/128 valid),
// BK=32 -> 12 K-steps. Both A and B staged via global_load_lds w=16 into
// XOR-swizzled 16B slots (slot s = (row=s>>2, q=(s&3)^((s>>3)&3)); frag read
// q = lq ^ ((l15>>1)&3) -> content q == lq since (row>>1)&3 == (l15>>1)&3;
// 2-way max bank aliasing, free). ONE barrier per K-step; the 16-MFMA cluster
// covers the in-flight staged loads; 32 KB LDS double-buffer -> 5 blocks/CU
// (~20 waves/CU TLP, vs 8 waves/CU in rounds 2-3).
// Grid (8, 168): x == XCD; y packs (bg, mt, nt) so one b's tiles share an XCD.
// ---------------------------------------------------------------------------
#define BM 128
#define BN 128
#define BK 32
#define KIT (CI_ / BK)     // 12

__global__ __launch_bounds__(256, 4) void moe_gemm3(const ushort_t* __restrict__ Agg,
                                                    const ushort_t* __restrict__ Xq,
                                                    float* __restrict__ Out) {
  __shared__ __align__(16) ushort_t As[2][BM * BK];  // 2 x 8 KB
  __shared__ __align__(16) ushort_t Bs[2][BN * BK];  // 2 x 8 KB

  const int tid  = threadIdx.x;
  const int lane = tid & 63;
  const int wave = tid >> 6;
  const int wm = wave & 1, wn = wave >> 1;

  const int bx = blockIdx.x;           // 0..7  == XCD id (linear%8 round-robin)
  const int by = blockIdx.y;           // 0..167
  const int bg  = by / 21;
  const int rem = by - bg * 21;
  const int mt  = rem / 7;             // 0..2
  const int nt  = rem - mt * 7;        // 0..6
  const int b   = bg * 8 + bx;

  // ---- staging slot decode (same for A and B): slot s = (row=s>>2, q=(s&3)^((s>>3)&3))
  const int sr0 = tid >> 2,          sq0 = (tid & 3) ^ ((tid >> 3) & 3);
  const int sr1 = (tid + 256) >> 2,  sq1 = (tid & 3) ^ (((tid + 256) >> 3) & 3);

  // A sources: row = co row, q = k-octet within BK
  const ushort_t* Ab = Agg + (size_t)b * CO_ * CI_ + (size_t)(mt * BM) * CI_;
  const ushort_t* Asrc0 = Ab + sr0 * CI_ + sq0 * 8;
  const ushort_t* Asrc1 = Ab + sr1 * CI_ + sq1 * 8;

  // B sources: row = hw col (clamped), q = g-offset within the 4-octet K-step
  int hw0 = nt * BN + sr0; hw0 = hw0 < HW_ ? hw0 : HW_ - 1;
  int hw1 = nt * BN + sr1; hw1 = hw1 < HW_ ? hw1 : HW_ - 1;
  const ushort_t* Xb = Xq + (size_t)b * G_ * HW_ * 8;
  const ushort_t* Bsrc0 = Xb + ((size_t)sq0 * HW_ + hw0) * 8;
  const ushort_t* Bsrc1 = Xb + ((size_t)sq1 * HW_ + hw1) * 8;

  // ---- fragment read coords ----
  const int l15 = lane & 15;
  const int lq  = lane >> 4;
  const int xqA = lq ^ ((l15 >> 1) & 3);   // swizzled q (valid for both A and B)

  f32x4 acc[4][4];
#pragma unroll
  for (int i = 0; i < 4; ++i)
#pragma unroll
    for (int j = 0; j < 4; ++j)
      acc[i][j] = (f32x4)0.f;

#define STAGE(PB, KK)                                                          \
  {                                                                            \
    __builtin_amdgcn_global_load_lds(                                          \
        (const __attribute__((address_space(1))) uint_t*)(Asrc0 + (KK) * BK),  \
        (__attribute__((address_space(3))) uint_t*)&As[PB][tid * 8], 16, 0, 0);\
    __builtin_amdgcn_global_load_lds(                                          \
        (const __attribute__((address_space(1))) uint_t*)(Asrc1 + (KK) * BK),  \
        (__attribute__((address_space(3))) uint_t*)&As[PB][(tid + 256) * 8],   \
        16, 0, 0);                                                             \
    const size_t bo_ = (size_t)(KK) * (4 * HW_ * 8);                           \
    __builtin_amdgcn_global_load_lds(                                          \
        (const __attribute__((address_space(1))) uint_t*)(Bsrc0 + bo_),        \
        (__attribute__((address_space(3))) uint_t*)&Bs[PB][tid * 8], 16, 0, 0);\
    __builtin_amdgcn_global_load_lds(                                          \
        (const __attribute__((address_space(1))) uint_t*)(Bsrc1 + bo_),        \
        (__attribute__((address_space(3))) uint_t*)&Bs[PB][(tid + 256) * 8],   \
        16, 0, 0);                                                             \
  }

  // ---- Prologue: stage tile 0 ----
  STAGE(0, 0);
  __syncthreads();   // compiler emits vmcnt(0) drain before s_barrier

  // ---- Main loop: ONE barrier per K-step; MFMA cluster covers next stage ----
#pragma unroll 1
  for (int kk = 0; kk < KIT; ++kk) {
    const int buf = kk & 1;
    if (kk + 1 < KIT) STAGE(1 - buf, kk + 1);

    bf16x8 a[4], bb[4];
#pragma unroll
    for (int mf = 0; mf < 4; ++mf) {
      const int row = wm * 64 + mf * 16 + l15;
      a[mf] = *(const bf16x8*)&As[buf][(row * 4 + xqA) * 8];
    }
#pragma unroll
    for (int nf = 0; nf < 4; ++nf) {
      const int col = wn * 64 + nf * 16 + l15;
      bb[nf] = *(const bf16x8*)&Bs[buf][(col * 4 + xqA) * 8];
    }
#pragma unroll
    for (int mf = 0; mf < 4; ++mf)
#pragma unroll
      for (int nf = 0; nf < 4; ++nf)
        acc[mf][nf] = __builtin_amdgcn_mfma_f32_16x16x32_bf16(a[mf], bb[nf],
                                                              acc[mf][nf], 0, 0, 0);
    __syncthreads();
  }

  // ---- Epilogue: C/D layout col=lane&15 (n), row=(lane>>4)*4+reg (m) ----
  float* Ob = Out + (size_t)b * CO_ * HW_;
#pragma unroll
  for (int mf = 0; mf < 4; ++mf) {
#pragma unroll
    for (int nf = 0; nf < 4; ++nf) {
      const int n = nt * BN + wn * 64 + nf * 16 + l15;
      if (n < HW_) {
        const int mbase = mt * BM + wm * 64 + mf * 16 + lq * 4;
#pragma unroll
        for (int r = 0; r < 4; ++r)
          Ob[(size_t)(mbase + r) * HW_ + n] = acc[mf][nf][r];
      }
    }
  }
}

// ---------------------------------------------------------------------------
// Workspace layout: agg bf16 [64][384][384] = 18.9 MB at offset 0,
//                   xq  bf16 [64][48][784][8] = 38.5 MB after it. (57.4 MB total)
// ---------------------------------------------------------------------------
extern "C" void kernel_launch(void* const* d_in, const int* in_sizes, int n_in,
                              void* d_out, int out_size, void* d_ws, size_t ws_size,
                              hipStream_t stream) {
  const float* x  = (const float*)d_in[0];  // [64,384,28,28] f32
  const float* rw = (const float*)d_in[1];  // [64,8] f32
  const float* w  = (const float*)d_in[2];  // [8,384,384] f32
  float* out = (float*)d_out;               // [64,384,28,28] f32

  ushort_t* agg = (ushort_t*)d_ws;
  ushort_t* xq  = agg + (size_t)B_ * CO_ * CI_;   // + 18.9 MB

  prep<<<AGG_BLOCKS + XQ_BLOCKS, 256, 0, stream>>>(rw, w, x, agg, xq);
  moe_gemm3<<<dim3(8, 21 * (B_ / 8)), 256, 0, stream>>>(agg, xq, out);
}

// Round 6
// 170.503 us; speedup vs baseline: 1.0643x; 1.0179x over previous
//
#include <hip/hip_runtime.h>
#include <cstdint>

// Problem constants
#define B_   64
#define CI_  384
#define CO_  384
#define HW_  784
#define E_   8
#define G_   (CI_ / 8)   // 48 ci-octets

typedef unsigned short ushort_t;
typedef unsigned int   uint_t;

typedef __attribute__((ext_vector_type(8))) short bf16x8;   // 8 bf16 (4 VGPRs)
typedef __attribute__((ext_vector_type(4))) float f32x4;    // MFMA accumulator

__device__ __forceinline__ ushort_t f2bf_rne(float f) {
  uint_t u = __builtin_bit_cast(uint_t, f);
  u += 0x7fffu + ((u >> 16) & 1u);
  return (ushort_t)(u >> 16);
}

// Pack truncated-bf16 of (f0 -> low ushort, f1 -> high ushort) in one v_perm_b32.
__device__ __forceinline__ uint_t pack_bf16_trunc(float f0, float f1) {
  return __builtin_amdgcn_perm(__builtin_bit_cast(uint_t, f1),   // S0 -> bytes 4..7
                               __builtin_bit_cast(uint_t, f0),   // S1 -> bytes 0..3
                               0x07060302u);                     // {f1.b3,f1.b2,f0.b3,f0.b2}
}

// ---------------------------------------------------------------------------
// Kernel 1 (fused prep) -- unchanged (near its 139 MB BW floor, ~24 us):
//  blocks [0, 288):    agg[b,o,i] = sum_e r[b,e]*w[e,o,i] -> bf16 (w read once).
//  blocks [288, 3360): xq[b][g][hw][j] = bf16(x[b][g*8+j][hw])  (ci-octet
//                      interleave: 16B chunk (g,hw) == one GEMM B-frag slice).
// ---------------------------------------------------------------------------
#define AGG_BLOCKS 288               // CO_*CI_/512
#define XQ_BLOCKS  (G_ * B_)         // 3072

__global__ __launch_bounds__(256) void prep(const float* __restrict__ rw,
                                            const float* __restrict__ w,
                                            const float* __restrict__ x,
                                            ushort_t* __restrict__ agg,
                                            ushort_t* __restrict__ xq) {
  __shared__ float r[B_ * E_];  // used by agg path only
  const int blk = blockIdx.x;
  const int tid = threadIdx.x;

  if (blk < AGG_BLOCKS) {
    r[tid]       = rw[tid];
    r[tid + 256] = rw[tid + 256];
    const int base = blk * 512 + tid * 2;  // flat (o,i) pair index
    float2 wv[E_];
#pragma unroll
    for (int e = 0; e < E_; ++e)
      wv[e] = *(const float2*)&w[e * (CO_ * CI_) + base];
    __syncthreads();
#pragma unroll 8
    for (int b = 0; b < B_; ++b) {
      float ax = 0.f, ay = 0.f;
#pragma unroll
      for (int e = 0; e < E_; ++e) {
        const float rv = r[b * E_ + e];
        ax += rv * wv[e].x;
        ay += rv * wv[e].y;
      }
      const uint_t v = (uint_t)f2bf_rne(ax) | ((uint_t)f2bf_rne(ay) << 16);
      *(uint_t*)&agg[(size_t)b * (CO_ * CI_) + base] = v;
    }
  } else {
    const int idx = blk - AGG_BLOCKS;
    const int g = idx % G_;
    const int b = idx / G_;
    const float* xp = x + ((size_t)b * CI_ + g * 8) * HW_;
    ushort_t* op = xq + (((size_t)b * G_ + g) * HW_) * 8;
#pragma unroll
    for (int c = 0; c < 4; ++c) {
      const int hw = c * 256 + tid;
      if (hw < HW_) {
        float v[8];
#pragma unroll
        for (int j = 0; j < 8; ++j) v[j] = xp[(size_t)j * HW_ + hw];
        uint4 u;
        u.x = pack_bf16_trunc(v[0], v[1]);
        u.y = pack_bf16_trunc(v[2], v[3]);
        u.z = pack_bf16_trunc(v[4], v[5]);
        u.w = pack_bf16_trunc(v[6], v[7]);
        *(uint4*)&op[hw * 8] = u;   // 16B chunk = one B-frag lane slice
      }
    }
  }
}

// ---------------------------------------------------------------------------
// Kernel 2: depth-2 counted-vmcnt GEMM (T4), 3-buffer LDS ring.
//   out[b](384x784) = agg[b](384x384 bf16) @ x[b] (as xq bf16)
// 256 thr = 4 waves 2x2, BM=BN=128, BK=32, 12 K-steps. Both operands DMA-
// staged (global_load_lds w=16, XOR-swizzled slots, zero VALU staging).
// Per K-step (wait-FIRST ordering):
//   s_waitcnt vmcnt(4)   <- retires stage t only; stage t+1 stays in flight
//   s_barrier            <- raw (no vmcnt(0) drain!)
//   STAGE(t+2)           <- ~2 iterations of latency cover per stage
//   ds_read frags + setprio'd 16-MFMA cluster
// Ring safety: stage t+2 writes buf (t-1)%3; its readers' ds_reads completed
// (lgkmcnt-waited before their MFMAs) before they arrived at barrier t, and
// the write is issued post-barrier-t -> WAR-safe. vmcnt: steady 8/thread
// outstanding (2 stages x 4 loads); tail drains 8->4->0 in peeled iters.
// LDS 48 KB -> 3 blocks/CU (12 waves/CU), VGPR ~120 under launch_bounds(256,3).
// Grid (8, 168): x == XCD; y packs (bg, mt, nt) so one b's tiles share an XCD.
// ---------------------------------------------------------------------------
#define BM 128
#define BN 128
#define BK 32
#define KIT (CI_ / BK)     // 12

__global__ __launch_bounds__(256, 3) void moe_gemm4(const ushort_t* __restrict__ Agg,
                                                    const ushort_t* __restrict__ Xq,
                                                    float* __restrict__ Out) {
  __shared__ __align__(16) ushort_t As[3][BM * BK];  // 3 x 8 KB
  __shared__ __align__(16) ushort_t Bs[3][BN * BK];  // 3 x 8 KB

  const int tid  = threadIdx.x;
  const int lane = tid & 63;
  const int wave = tid >> 6;
  const int wm = wave & 1, wn = wave >> 1;

  const int bx = blockIdx.x;           // 0..7  == XCD id (linear%8 round-robin)
  const int by = blockIdx.y;           // 0..167
  const int bg  = by / 21;
  const int rem = by - bg * 21;
  const int mt  = rem / 7;             // 0..2
  const int nt  = rem - mt * 7;        // 0..6
  const int b   = bg * 8 + bx;

  // ---- staging slot decode (A and B): slot s = (row=s>>2, q=(s&3)^((s>>3)&3))
  const int sr0 = tid >> 2,          sq0 = (tid & 3) ^ ((tid >> 3) & 3);
  const int sr1 = (tid + 256) >> 2,  sq1 = (tid & 3) ^ (((tid + 256) >> 3) & 3);

  // A sources: row = co row, q = k-octet within BK
  const ushort_t* Ab = Agg + (size_t)b * CO_ * CI_ + (size_t)(mt * BM) * CI_;
  const ushort_t* Asrc0 = Ab + sr0 * CI_ + sq0 * 8;
  const ushort_t* Asrc1 = Ab + sr1 * CI_ + sq1 * 8;

  // B sources: row = hw col (clamped), q = g-offset within the 4-octet K-step
  int hw0 = nt * BN + sr0; hw0 = hw0 < HW_ ? hw0 : HW_ - 1;
  int hw1 = nt * BN + sr1; hw1 = hw1 < HW_ ? hw1 : HW_ - 1;
  const ushort_t* Xb = Xq + (size_t)b * G_ * HW_ * 8;
  const ushort_t* Bsrc0 = Xb + ((size_t)sq0 * HW_ + hw0) * 8;
  const ushort_t* Bsrc1 = Xb + ((size_t)sq1 * HW_ + hw1) * 8;

  // ---- fragment read coords ----
  const int l15 = lane & 15;
  const int lq  = lane >> 4;
  const int xqA = lq ^ ((l15 >> 1) & 3);   // swizzled q (content q == lq)

  f32x4 acc[4][4];
#pragma unroll
  for (int i = 0; i < 4; ++i)
#pragma unroll
    for (int j = 0; j < 4; ++j)
      acc[i][j] = (f32x4)0.f;

#define STAGE(PB, KK)                                                          \
  {                                                                            \
    __builtin_amdgcn_global_load_lds(                                          \
        (const __attribute__((address_space(1))) uint_t*)(Asrc0 + (KK) * BK),  \
        (__attribute__((address_space(3))) uint_t*)&As[PB][tid * 8], 16, 0, 0);\
    __builtin_amdgcn_global_load_lds(                                          \
        (const __attribute__((address_space(1))) uint_t*)(Asrc1 + (KK) * BK),  \
        (__attribute__((address_space(3))) uint_t*)&As[PB][(tid + 256) * 8],   \
        16, 0, 0);                                                             \
    const size_t bo_ = (size_t)(KK) * (4 * HW_ * 8);                           \
    __builtin_amdgcn_global_load_lds(                                          \
        (const __attribute__((address_space(1))) uint_t*)(Bsrc0 + bo_),        \
        (__attribute__((address_space(3))) uint_t*)&Bs[PB][tid * 8], 16, 0, 0);\
    __builtin_amdgcn_global_load_lds(                                          \
        (const __attribute__((address_space(1))) uint_t*)(Bsrc1 + bo_),        \
        (__attribute__((address_space(3))) uint_t*)&Bs[PB][(tid + 256) * 8],   \
        16, 0, 0);                                                             \
  }

#define COMPUTE(CB)                                                            \
  {                                                                            \
    bf16x8 a[4], bb[4];                                                        \
    _Pragma("unroll") for (int mf = 0; mf < 4; ++mf) {                         \
      const int row = wm * 64 + mf * 16 + l15;                                 \
      a[mf] = *(const bf16x8*)&As[CB][(row * 4 + xqA) * 8];                    \
    }                                                                          \
    _Pragma("unroll") for (int nf = 0; nf < 4; ++nf) {                         \
      const int col = wn * 64 + nf * 16 + l15;                                 \
      bb[nf] = *(const bf16x8*)&Bs[CB][(col * 4 + xqA) * 8];                   \
    }                                                                          \
    __builtin_amdgcn_s_setprio(1);                                             \
    _Pragma("unroll") for (int mf = 0; mf < 4; ++mf)                           \
      _Pragma("unroll") for (int nf = 0; nf < 4; ++nf)                         \
        acc[mf][nf] = __builtin_amdgcn_mfma_f32_16x16x32_bf16(a[mf], bb[nf],   \
                                                              acc[mf][nf],     \
                                                              0, 0, 0);        \
    __builtin_amdgcn_s_setprio(0);                                             \
  }

// One K-step. VM is a literal (4 steady-state, 0 for the last drain).
// wait own stage-t loads -> barrier (all waves' stage t landed) -> fence ->
// issue stage t+2 (2 iters of cover) -> compute tile t.
#define ITER_S(VM, CB, STG)                                                    \
  {                                                                            \
    asm volatile("s_waitcnt vmcnt(" #VM ")" ::: "memory");                     \
    __builtin_amdgcn_s_barrier();                                              \
    __builtin_amdgcn_sched_barrier(0);                                         \
    STAGE((STG) % 3, STG);                                                     \
    COMPUTE(CB);                                                               \
    __builtin_amdgcn_sched_barrier(0);                                         \
  }
#define ITER_N(VM, CB)                                                         \
  {                                                                            \
    asm volatile("s_waitcnt vmcnt(" #VM ")" ::: "memory");                     \
    __builtin_amdgcn_s_barrier();                                              \
    __builtin_amdgcn_sched_barrier(0);                                         \
    COMPUTE(CB);                                                               \
    __builtin_amdgcn_sched_barrier(0);                                         \
  }

  // ---- Prologue: stages 0,1 in flight (8 loads/thread outstanding) ----
  STAGE(0, 0);
  STAGE(1, 1);

  // ---- Main: t = 0..9 compute tile t, stage tile t+2 (fully unrolled so
  //      t%3 and (t+2)*BK fold to constants) ----
#pragma unroll
  for (int t = 0; t < 10; ++t)
    ITER_S(4, t % 3, t + 2);

  // ---- Drain: t=10 (stage 11 still in flight), t=11 (wait all) ----
  ITER_N(4, 1);
  ITER_N(0, 2);

  // ---- Epilogue: C/D layout col=lane&15 (n), row=(lane>>4)*4+reg (m) ----
  float* Ob = Out + (size_t)b * CO_ * HW_;
#pragma unroll
  for (int mf = 0; mf < 4; ++mf) {
#pragma unroll
    for (int nf = 0; nf < 4; ++nf) {
      const int n = nt * BN + wn * 64 + nf * 16 + l15;
      if (n < HW_) {
        const int mbase = mt * BM + wm * 64 + mf * 16 + lq * 4;
#pragma unroll
        for (int r = 0; r < 4; ++r)
          Ob[(size_t)(mbase + r) * HW_ + n] = acc[mf][nf][r];
      }
    }
  }
}

// ---------------------------------------------------------------------------
// Workspace layout: agg bf16 [64][384][384] = 18.9 MB at offset 0,
//                   xq  bf16 [64][48][784][8] = 38.5 MB after it. (57.4 MB total)
// ---------------------------------------------------------------------------
extern "C" void kernel_launch(void* const* d_in, const int* in_sizes, int n_in,
                              void* d_out, int out_size, void* d_ws, size_t ws_size,
                              hipStream_t stream) {
  const float* x  = (const float*)d_in[0];  // [64,384,28,28] f32
  const float* rw = (const float*)d_in[1];  // [64,8] f32
  const float* w  = (const float*)d_in[2];  // [8,384,384] f32
  float* out = (float*)d_out;               // [64,384,28,28] f32

  ushort_t* agg = (ushort_t*)d_ws;
  ushort_t* xq  = agg + (size_t)B_ * CO_ * CI_;   // + 18.9 MB

  prep<<<AGG_BLOCKS + XQ_BLOCKS, 256, 0, stream>>>(rw, w, x, agg, xq);
  moe_gemm4<<<dim3(8, 21 * (B_ / 8)), 256, 0, stream>>>(agg, xq, out);
}